// Round 10
// baseline (378.860 us; speedup 1.0000x reference)
//
#include <hip/hip_runtime.h>
#include <hip/hip_bf16.h>

#define N_NODES 100000
#define N_EDGES 1600000
#define NFEAT   128
#define NGRAPH  256
#define NACT    32
#define ECAP    64
#define OVF_CAP 8192

// ---- two-pass edge partition ----
#define BUCK_SHIFT 9
#define BUCK_NODES 512
#define NBUCK ((N_NODES + BUCK_NODES - 1) / BUCK_NODES)   // 196
#define SEGCAP 10240          // mean 8192, +22 sigma
#define CHUNK 4096            // edges per pass-1 block
#define NBLK1 ((N_EDGES + CHUNK - 1) / CHUNK)             // 391
#define BIN_NODES 128         // pass-2 nodes per block
#define NBLK2 ((N_NODES + BIN_NODES - 1) / BIN_NODES)     // 782

typedef __attribute__((ext_vector_type(8))) short bf16x8;
typedef __attribute__((ext_vector_type(4))) float f32x4;

__device__ inline unsigned short f2bf(float f) {
  __hip_bfloat16 b = __float2bfloat16(f);
  return *reinterpret_cast<unsigned short*>(&b);
}
__device__ inline float2 bfu2f(unsigned u) {
  __hip_bfloat162 t = *reinterpret_cast<__hip_bfloat162*>(&u);
  return __bfloat1622float2(t);
}

// ---- pass 1: block-local bucket sort in LDS, dense segment flush ----
// No per-thread edge array (scratch-spill trap, R6); phase C re-reads edges.
__global__ __launch_bounds__(256) void edgepart_kernel(const int* __restrict__ src,
                                                       const int* __restrict__ dst,
                                                       int* __restrict__ bucket_cursor,
                                                       int2* __restrict__ seg,
                                                       int* __restrict__ cnt,
                                                       int* __restrict__ ovf_cnt,
                                                       int* __restrict__ ovf) {
  __shared__ int2 stage[CHUNK];               // 32 KB
  __shared__ int hist[NBUCK], offs[NBUCK], cursor[NBUCK], gbase[NBUCK];
  __shared__ int sc[256];
  int tid = threadIdx.x;
  int e0 = blockIdx.x * CHUNK;
  int m = N_EDGES - e0; if (m > CHUNK) m = CHUNK;

  for (int i = tid; i < NBUCK; i += 256) hist[i] = 0;
  __syncthreads();

  for (int i = tid; i < m; i += 256)
    atomicAdd(&hist[dst[e0 + i] >> BUCK_SHIFT], 1);
  __syncthreads();

  sc[tid] = (tid < NBUCK) ? hist[tid] : 0;
  __syncthreads();
  for (int ofs = 1; ofs < 256; ofs <<= 1) {
    int t = (tid >= ofs) ? sc[tid - ofs] : 0;
    __syncthreads();
    sc[tid] += t;
    __syncthreads();
  }
  if (tid < NBUCK) {
    int o = tid ? sc[tid - 1] : 0;
    offs[tid] = o;
    cursor[tid] = o;
    gbase[tid] = hist[tid] ? atomicAdd(&bucket_cursor[tid], hist[tid]) : 0;
  }
  __syncthreads();

  for (int i = tid; i < m; i += 256) {
    int2 p = make_int2(src[e0 + i], dst[e0 + i]);
    int pos = atomicAdd(&cursor[p.y >> BUCK_SHIFT], 1);
    stage[pos] = p;
  }
  __syncthreads();

  for (int i = tid; i < m; i += 256) {
    int2 p = stage[i];
    int bd = p.y >> BUCK_SHIFT;
    int gpos = gbase[bd] + (i - offs[bd]);
    if (gpos < SEGCAP) {
      seg[(size_t)bd * SEGCAP + gpos] = p;
    } else {                                // ~never: count + defer to ovf fixup
      atomicAdd(&cnt[p.y], 1);
      int o = atomicAdd(ovf_cnt, 1);
      if (o < OVF_CAP) { ovf[2 * o] = p.x; ovf[2 * o + 1] = p.y; }
    }
  }
}

// ---- pass 2: per-128-node elist build in LDS, dense writeback (+dinv fused) ----
__global__ __launch_bounds__(256) void binbuild_kernel(const int2* __restrict__ seg,
                                                       const int* __restrict__ bucket_cursor,
                                                       int* __restrict__ cnt,
                                                       float* __restrict__ dinv,
                                                       int* __restrict__ elist,
                                                       int* __restrict__ ovf_cnt,
                                                       int* __restrict__ ovf) {
  __shared__ int lcnt[BIN_NODES];
  __shared__ int lel[BIN_NODES * ECAP];     // 32 KB
  int tid = threadIdx.x;
  int n0 = blockIdx.x * BIN_NODES;
  int pb = n0 >> BUCK_SHIFT;
  if (tid < BIN_NODES) lcnt[tid] = 0;
  __syncthreads();
  int m = bucket_cursor[pb]; if (m > SEGCAP) m = SEGCAP;
  const int2* s = seg + (size_t)pb * SEGCAP;
  for (int e = tid; e < m; e += 256) {
    int2 p = s[e];
    unsigned ln = (unsigned)(p.y - n0);
    if (ln < (unsigned)BIN_NODES) {
      int pos = atomicAdd(&lcnt[ln], 1);
      if (pos < ECAP) {
        lel[(ln << 6) + pos] = p.x;
      } else {
        int o = atomicAdd(ovf_cnt, 1);
        if (o < OVF_CAP) { ovf[2 * o] = p.x; ovf[2 * o + 1] = p.y; }
      }
    }
  }
  __syncthreads();
  if (tid < BIN_NODES) {
    int n = n0 + tid;
    if (n < N_NODES) {
      int tot = cnt[n] + lcnt[tid];          // cnt[n]: pass-1 ovf-capped edges only
      cnt[n] = tot;                          // safe: block owns node range
      dinv[n] = rsqrtf((float)tot + 1.0f);   // fused dinv
    }
  }
  int4* gel = (int4*)(elist + (size_t)n0 * ECAP);
  const int4* lel4 = (const int4*)lel;
  for (int i = tid; i < BIN_NODES * ECAP / 4; i += 256) gel[i] = lel4[i];
}

// ---------------- Wt[n][k] = bf16(W[k][n]) for both layers, one launch --------
__global__ __launch_bounds__(256) void wt2_kernel(const float* __restrict__ W1,
                                                  const float* __restrict__ W2,
                                                  unsigned short* __restrict__ Wt1,
                                                  unsigned short* __restrict__ Wt2) {
  int i = blockIdx.x * 256 + threadIdx.x;
  int which = i >> 14;                 // 16384 elems per matrix
  int idx = i & 16383;
  int n = idx >> 7, k = idx & 127;
  if (which == 0) Wt1[n * NFEAT + k] = f2bf(W1[k * NFEAT + n]);
  else            Wt2[n * NFEAT + k] = f2bf(W2[k * NFEAT + n]);
}

// ---------------- layer-1 GEMM: C(bf16) = A(f32) @ W via MFMA ------------
__global__ __launch_bounds__(256) void gemm_f32in_kernel(const float* __restrict__ A,
                                                         const unsigned short* __restrict__ Wt,
                                                         unsigned short* __restrict__ C) {
  int tid = threadIdx.x;
  int wave = tid >> 6, lane = tid & 63;
  int q = lane >> 4, r = lane & 15;
  int m0 = blockIdx.x * 64 + wave * 16;
  int arow = m0 + r; if (arow > N_NODES - 1) arow = N_NODES - 1;
  const float* Arow = A + (size_t)arow * NFEAT;

  f32x4 acc[8];
  #pragma unroll
  for (int t = 0; t < 8; ++t) acc[t] = (f32x4){0.f, 0.f, 0.f, 0.f};

  #pragma unroll
  for (int s = 0; s < 4; ++s) {
    int k0 = s * 32 + q * 8;
    float4 a0 = *(const float4*)(Arow + k0);
    float4 a1 = *(const float4*)(Arow + k0 + 4);
    bf16x8 af;
    af[0] = (short)f2bf(a0.x); af[1] = (short)f2bf(a0.y);
    af[2] = (short)f2bf(a0.z); af[3] = (short)f2bf(a0.w);
    af[4] = (short)f2bf(a1.x); af[5] = (short)f2bf(a1.y);
    af[6] = (short)f2bf(a1.z); af[7] = (short)f2bf(a1.w);
    #pragma unroll
    for (int t = 0; t < 8; ++t) {
      bf16x8 bf = *(const bf16x8*)(Wt + (size_t)(t * 16 + r) * NFEAT + k0);
      acc[t] = __builtin_amdgcn_mfma_f32_16x16x32_bf16(af, bf, acc[t], 0, 0, 0);
    }
  }
  #pragma unroll
  for (int t = 0; t < 8; ++t)
    #pragma unroll
    for (int rr = 0; rr < 4; ++rr) {
      int row = m0 + q * 4 + rr;
      if (row < N_NODES)
        C[(size_t)row * NFEAT + t * 16 + r] = f2bf(acc[t][rr]);
    }
}

// ---------------- layer-2 GEMM: C(bf16) = relu(A(bf16)) @ W via MFMA ----------
__global__ __launch_bounds__(256) void gemm_bf16in_kernel(const unsigned short* __restrict__ A,
                                                          const unsigned short* __restrict__ Wt,
                                                          unsigned short* __restrict__ C) {
  int tid = threadIdx.x;
  int wave = tid >> 6, lane = tid & 63;
  int q = lane >> 4, r = lane & 15;
  int m0 = blockIdx.x * 64 + wave * 16;
  int arow = m0 + r; if (arow > N_NODES - 1) arow = N_NODES - 1;
  const unsigned short* Arow = A + (size_t)arow * NFEAT;

  f32x4 acc[8];
  #pragma unroll
  for (int t = 0; t < 8; ++t) acc[t] = (f32x4){0.f, 0.f, 0.f, 0.f};

  #pragma unroll
  for (int s = 0; s < 4; ++s) {
    int k0 = s * 32 + q * 8;
    bf16x8 af = *(const bf16x8*)(Arow + k0);   // direct 16B bf16 load
    #pragma unroll
    for (int i = 0; i < 8; ++i)                // relu: bf16 sign bit == short sign
      af[i] = (short)(af[i] < (short)0 ? (short)0 : af[i]);
    #pragma unroll
    for (int t = 0; t < 8; ++t) {
      bf16x8 bf = *(const bf16x8*)(Wt + (size_t)(t * 16 + r) * NFEAT + k0);
      acc[t] = __builtin_amdgcn_mfma_f32_16x16x32_bf16(af, bf, acc[t], 0, 0, 0);
    }
  }
  #pragma unroll
  for (int t = 0; t < 8; ++t)
    #pragma unroll
    for (int rr = 0; rr < 4; ++rr) {
      int row = m0 + q * 4 + rr;
      if (row < N_NODES)
        C[(size_t)row * NFEAT + t * 16 + r] = f2bf(acc[t][rr]);
    }
}

// ---------------- gather aggregation: QUARTER-WAVE per node ----------------
// 4 nodes/wave, 16 lanes/node, uint4 (8 feats) per lane: one load instruction
// serves 4 edges; one shfl pair serves 4 edges. Gather granularity stays 256B
// per node segment. Slots >= c padded with (s=n, w=0).
__global__ __launch_bounds__(256) void agg_kernel(const uint4* __restrict__ h4,
                                                  const int* __restrict__ elist,
                                                  const int* __restrict__ cnt,
                                                  const float* __restrict__ dinv,
                                                  const float* __restrict__ bias,
                                                  uint4* __restrict__ out) {
  int wid = (blockIdx.x * 256 + threadIdx.x) >> 6;
  int lane = threadIdx.x & 63;
  int hl = lane & 15;
  int n = wid * 4 + (lane >> 4);
  if (n >= N_NODES) return;
  float dn = dinv[n];
  int c = cnt[n]; c = (c > ECAP) ? ECAP : c;
  const int* el = elist + (size_t)n * ECAP;

  // lane-parallel prefetch: quarter g covers slots [16g, 16g+16)
  int s[4]; float w[4];
  #pragma unroll
  for (int g = 0; g < 4; ++g) {
    int idx = hl + 16 * g;
    s[g] = (idx < c) ? el[idx] : n;
    w[g] = (idx < c) ? dinv[s[g]] * dn : 0.f;
  }
  int cmax = __shfl(c, 0);
  cmax = max(cmax, __shfl(c, 16));
  cmax = max(cmax, __shfl(c, 32));
  cmax = max(cmax, __shfl(c, 48));

  uint4 hv = h4[(size_t)n * 16 + hl];
  float2 p0 = bfu2f(hv.x), p1 = bfu2f(hv.y), p2 = bfu2f(hv.z), p3 = bfu2f(hv.w);
  float sw = dn * dn;
  float a0 = sw * p0.x, a1 = sw * p0.y, a2 = sw * p1.x, a3 = sw * p1.y;
  float a4 = sw * p2.x, a5 = sw * p2.y, a6 = sw * p3.x, a7 = sw * p3.y;

  #pragma unroll
  for (int g = 0; g < 4; ++g) {
    int base = g * 16;
    if (base >= cmax) break;
    int e = cmax - base; if (e > 16) e = 16;
    int j = 0;
    for (; j + 4 <= e; j += 4) {
      uint4 pv[4]; float wv[4];
      #pragma unroll
      for (int u = 0; u < 4; ++u) {
        int ss = __shfl(s[g], j + u, 16);     // per-quarter broadcast
        wv[u] = __shfl(w[g], j + u, 16);
        pv[u] = h4[(size_t)ss * 16 + hl];     // 4 independent 1KB/wave gathers
      }
      #pragma unroll
      for (int u = 0; u < 4; ++u) {
        float2 q0 = bfu2f(pv[u].x), q1 = bfu2f(pv[u].y);
        float2 q2 = bfu2f(pv[u].z), q3 = bfu2f(pv[u].w);
        a0 = fmaf(wv[u], q0.x, a0); a1 = fmaf(wv[u], q0.y, a1);
        a2 = fmaf(wv[u], q1.x, a2); a3 = fmaf(wv[u], q1.y, a3);
        a4 = fmaf(wv[u], q2.x, a4); a5 = fmaf(wv[u], q2.y, a5);
        a6 = fmaf(wv[u], q3.x, a6); a7 = fmaf(wv[u], q3.y, a7);
      }
    }
    for (; j < e; ++j) {
      int ss = __shfl(s[g], j, 16);
      float ww = __shfl(w[g], j, 16);
      uint4 pv = h4[(size_t)ss * 16 + hl];
      float2 q0 = bfu2f(pv.x), q1 = bfu2f(pv.y);
      float2 q2 = bfu2f(pv.z), q3 = bfu2f(pv.w);
      a0 = fmaf(ww, q0.x, a0); a1 = fmaf(ww, q0.y, a1);
      a2 = fmaf(ww, q1.x, a2); a3 = fmaf(ww, q1.y, a3);
      a4 = fmaf(ww, q2.x, a4); a5 = fmaf(ww, q2.y, a5);
      a6 = fmaf(ww, q3.x, a6); a7 = fmaf(ww, q3.y, a7);
    }
  }
  const float4* b4 = (const float4*)bias;
  float4 ba = b4[hl * 2], bb = b4[hl * 2 + 1];
  uint4 r;
  r.x = ((unsigned)f2bf(a1 + ba.y) << 16) | f2bf(a0 + ba.x);
  r.y = ((unsigned)f2bf(a3 + ba.w) << 16) | f2bf(a2 + ba.z);
  r.z = ((unsigned)f2bf(a5 + bb.y) << 16) | f2bf(a4 + bb.x);
  r.w = ((unsigned)f2bf(a7 + bb.w) << 16) | f2bf(a6 + bb.z);
  out[(size_t)n * 16 + hl] = r;
}

// ---------------- overflow edges (runs 0 times on this input) ----------------
__device__ void bf16_atomic_add(unsigned short* addr, float val) {
  unsigned* word = (unsigned*)((size_t)addr & ~(size_t)3);
  bool hi = ((size_t)addr & 2) != 0;
  unsigned old = *word, assumed;
  do {
    assumed = old;
    unsigned short cur = hi ? (unsigned short)(assumed >> 16)
                            : (unsigned short)(assumed & 0xFFFF);
    __hip_bfloat16 bb = *reinterpret_cast<__hip_bfloat16*>(&cur);
    unsigned short nb = f2bf(__bfloat162float(bb) + val);
    unsigned newv = hi ? ((assumed & 0x0000FFFFu) | ((unsigned)nb << 16))
                       : ((assumed & 0xFFFF0000u) | nb);
    old = atomicCAS(word, assumed, newv);
  } while (old != assumed);
}

__global__ __launch_bounds__(128) void ovf_kernel(const unsigned short* __restrict__ h,
                                                  const int* __restrict__ ovf,
                                                  const int* __restrict__ ovf_cnt,
                                                  const float* __restrict__ dinv,
                                                  unsigned short* __restrict__ out) {
  int m = *ovf_cnt; if (m > OVF_CAP) m = OVF_CAP;
  for (int p = blockIdx.x; p < m; p += gridDim.x) {
    int s = ovf[2 * p], d = ovf[2 * p + 1];
    float w = dinv[s] * dinv[d];
    for (int f = threadIdx.x; f < NFEAT; f += blockDim.x) {
      unsigned short hs = h[(size_t)s * NFEAT + f];
      __hip_bfloat16 hb = *reinterpret_cast<__hip_bfloat16*>(&hs);
      bf16_atomic_add(&out[(size_t)d * NFEAT + f], w * __bfloat162float(hb));
    }
  }
}

// ---------------- pooled sum of relu(h) by (sorted) batch, h bf16 --------------
#define PCHUNK 64
__global__ __launch_bounds__(64) void pool_kernel(const unsigned* __restrict__ hu,
                                                  const int* __restrict__ batch,
                                                  float* __restrict__ gsum) {
  int lane = threadIdx.x;
  int n0 = blockIdx.x * PCHUNK;
  if (n0 >= N_NODES) return;
  int n1 = n0 + PCHUNK; if (n1 > N_NODES) n1 = N_NODES;
  float ax = 0.f, ay = 0.f;
  int cur = batch[n0];
  for (int n = n0; n < n1; ++n) {
    int b = batch[n];
    if (b != cur) {
      atomicAdd(&gsum[cur * NFEAT + 2 * lane], ax);
      atomicAdd(&gsum[cur * NFEAT + 2 * lane + 1], ay);
      ax = 0.f; ay = 0.f; cur = b;
    }
    float2 v = bfu2f(hu[(size_t)n * 64 + lane]);
    ax += fmaxf(v.x, 0.f);
    ay += fmaxf(v.y, 0.f);
  }
  atomicAdd(&gsum[cur * NFEAT + 2 * lane], ax);
  atomicAdd(&gsum[cur * NFEAT + 2 * lane + 1], ay);
}

// ---------------- MLP head (graph-count binary search fused in) ----------------
__global__ __launch_bounds__(128) void mlp_kernel(const float* __restrict__ gsum,
                                                  const int* __restrict__ batch,
                                                  const float* __restrict__ Wl1,
                                                  const float* __restrict__ bl1,
                                                  const float* __restrict__ Wl2,
                                                  const float* __restrict__ bl2,
                                                  float* __restrict__ out) {
  __shared__ float gr[NFEAT];
  __shared__ float t1[NFEAT];
  __shared__ float sinv;
  int g = blockIdx.x, t = threadIdx.x;
  if (t == 0) {
    int lo = 0, hi = N_NODES;
    while (lo < hi) { int mid = (lo + hi) >> 1; if (batch[mid] < g) lo = mid + 1; else hi = mid; }
    int lo2 = lo, hi2 = N_NODES;
    while (lo2 < hi2) { int mid = (lo2 + hi2) >> 1; if (batch[mid] < g + 1) lo2 = mid + 1; else hi2 = mid; }
    sinv = 1.0f / fmaxf((float)(lo2 - lo), 1.0f);
  }
  __syncthreads();
  gr[t] = gsum[g * NFEAT + t] * sinv;
  __syncthreads();
  float acc = bl1[t];
  for (int k = 0; k < NFEAT; ++k) acc = fmaf(gr[k], Wl1[k * NFEAT + t], acc);
  t1[t] = fmaxf(acc, 0.f);
  __syncthreads();
  if (t < NACT) {
    float a2 = bl2[t];
    for (int k = 0; k < NFEAT; ++k) a2 = fmaf(t1[k], Wl2[k * NACT + t], a2);
    out[g * NACT + t] = a2;
  }
}

extern "C" void kernel_launch(void* const* d_in, const int* in_sizes, int n_in,
                              void* d_out, int out_size, void* d_ws, size_t ws_size,
                              hipStream_t stream) {
  const float* x    = (const float*)d_in[0];
  const int*   ei   = (const int*)d_in[1];
  const int*   batch= (const int*)d_in[2];
  const float* W1   = (const float*)d_in[3];
  const float* b1   = (const float*)d_in[4];
  const float* W2   = (const float*)d_in[5];
  const float* b2   = (const float*)d_in[6];
  const float* Wl1  = (const float*)d_in[7];
  const float* bl1  = (const float*)d_in[8];
  const float* Wl2  = (const float*)d_in[9];
  const float* bl2  = (const float*)d_in[10];
  float* out = (float*)d_out;

  const int* srcp = ei;            // edge_index[0]
  const int* dstp = ei + N_EDGES;  // edge_index[1]

  char* base = (char*)d_ws;
  size_t off = 0;
  auto alloc = [&](size_t bytes) -> void* {
    void* p = base + off;
    off += (bytes + 511) & ~(size_t)511;
    return p;
  };
  int*   cnt     = (int*)alloc((size_t)N_NODES * 4);
  int*   ovfc    = (int*)alloc(4);
  float* gsum    = (float*)alloc((size_t)NGRAPH * NFEAT * 4);
  int*   bucket_cursor = (int*)alloc((size_t)NBUCK * 4);
  size_t zspan   = off;  // everything above must start zeroed
  float* dinv    = (float*)alloc((size_t)N_NODES * 4);
  int*   elist   = (int*)alloc((size_t)NBLK2 * BIN_NODES * ECAP * 4); // padded
  int*   ovf     = (int*)alloc((size_t)OVF_CAP * 2 * 4);
  int2*  seg     = (int2*)alloc((size_t)NBUCK * SEGCAP * 8);          // 16 MB
  unsigned short* Wt1 = (unsigned short*)alloc((size_t)NFEAT * NFEAT * 2);
  unsigned short* Wt2 = (unsigned short*)alloc((size_t)NFEAT * NFEAT * 2);
  unsigned short* A = (unsigned short*)alloc((size_t)N_NODES * NFEAT * 2); // bf16
  unsigned short* B = (unsigned short*)alloc((size_t)N_NODES * NFEAT * 2); // bf16

  hipMemsetAsync(d_ws, 0, zspan, stream);

  const int GB = (N_NODES + 63) / 64;     // 1563 gemm blocks
  const int AB = (N_NODES + 15) / 16;     // 6250 agg blocks (16 nodes/block)

  edgepart_kernel<<<NBLK1, 256, 0, stream>>>(srcp, dstp, bucket_cursor, seg, cnt, ovfc, ovf);
  binbuild_kernel<<<NBLK2, 256, 0, stream>>>(seg, bucket_cursor, cnt, dinv, elist, ovfc, ovf);
  wt2_kernel<<<2 * NFEAT * NFEAT / 256, 256, 0, stream>>>(W1, W2, Wt1, Wt2);

  // layer 1: A = x @ W1 ; B = agg(A) + selfloop + b1 (relu deferred to gemm2)
  gemm_f32in_kernel<<<GB, 256, 0, stream>>>(x, Wt1, A);
  agg_kernel<<<AB, 256, 0, stream>>>((const uint4*)A, elist, cnt, dinv, b1, (uint4*)B);
  ovf_kernel<<<64, 128, 0, stream>>>(A, ovf, ovfc, dinv, B);

  // layer 2: A = relu(B) @ W2 ; B = agg(A) + selfloop + b2 (relu at pool)
  gemm_bf16in_kernel<<<GB, 256, 0, stream>>>(B, Wt2, A);
  agg_kernel<<<AB, 256, 0, stream>>>((const uint4*)A, elist, cnt, dinv, b2, (uint4*)B);
  ovf_kernel<<<64, 128, 0, stream>>>(A, ovf, ovfc, dinv, B);

  // pool + head
  pool_kernel<<<(N_NODES + PCHUNK - 1) / PCHUNK, 64, 0, stream>>>((const unsigned*)B, batch, gsum);
  mlp_kernel<<<NGRAPH, 128, 0, stream>>>(gsum, batch, Wl1, bl1, Wl2, bl2, out);
}